// Round 1
// baseline (46479.291 us; speedup 1.0000x reference)
//
#include <hip/hip_runtime.h>
#include <math.h>

#define TSTEPS 1024
#define BB 256
#define HH 256
#define INPUT 16

// ---- workspace layout (float offsets) ----
// Wg1s  [256 j][128 kq][4 gate][4 ki]  : L1 weights, concat(W_ih1, W_hh1) along k
// Wg0hs [256 j][ 64 kq][4][4]          : L0 recurrent weights
// Wg0xs [256 j][  4 kq][4][4]          : L0 input weights
// bs0/bs1 [256 j][4 gate]              : summed biases b_ih + b_hh
// h0/h1 [2 buf][256 r][256 j]          : double-buffered hidden states
// c0T/c1T [256 j][256 r]               : cell states, transposed for coalesced lane=row access
// pbuf [2][8 jb][256 r]                : fc2 partials
#define OFF_WG1S  0u
#define OFF_WG0HS 524288u
#define OFF_WG0XS 786432u
#define OFF_BS0   802816u
#define OFF_BS1   803840u
#define OFF_H0    804864u
#define OFF_H1    935936u
#define OFF_C0T   1067008u
#define OFF_C1T   1132544u
#define OFF_PB    1198080u
#define WS_FLOATS 1202176u

__device__ __forceinline__ float sigmoidf_(float v) {
    return 1.0f / (1.0f + expf(-v));
}

__global__ __launch_bounds__(256) void prep_kernel(
    const float* __restrict__ Wih0, const float* __restrict__ Whh0,
    const float* __restrict__ bih0, const float* __restrict__ bhh0,
    const float* __restrict__ Wih1, const float* __restrict__ Whh1,
    const float* __restrict__ bih1, const float* __restrict__ bhh1,
    float* __restrict__ ws)
{
    for (unsigned idx = blockIdx.x * blockDim.x + threadIdx.x; idx < 804864u;
         idx += gridDim.x * blockDim.x) {
        if (idx < 524288u) {                       // Wg1s
            unsigned j = idx >> 11, rem = idx & 2047u;
            unsigned kq = rem >> 4, g = (rem >> 2) & 3u, ki = rem & 3u;
            unsigned k = kq * 4 + ki, row = g * 256 + j;
            ws[idx] = (k < 256u) ? Wih1[row * 256 + k] : Whh1[row * 256 + (k - 256u)];
        } else if (idx < 786432u) {                // Wg0hs
            unsigned i2 = idx - 524288u;
            unsigned j = i2 >> 10, rem = i2 & 1023u;
            unsigned kq = rem >> 4, g = (rem >> 2) & 3u, ki = rem & 3u;
            unsigned k = kq * 4 + ki, row = g * 256 + j;
            ws[idx] = Whh0[row * 256 + k];
        } else if (idx < 802816u) {                // Wg0xs
            unsigned i2 = idx - 786432u;
            unsigned j = i2 >> 6, rem = i2 & 63u;
            unsigned kq = rem >> 4, g = (rem >> 2) & 3u, ki = rem & 3u;
            unsigned k = kq * 4 + ki, row = g * 256 + j;
            ws[idx] = Wih0[row * 16 + k];
        } else if (idx < 803840u) {                // bs0
            unsigned i2 = idx - 802816u;
            unsigned j = i2 >> 2, g = i2 & 3u, row = g * 256 + j;
            ws[idx] = bih0[row] + bhh0[row];
        } else {                                   // bs1
            unsigned i2 = idx - 803840u;
            unsigned j = i2 >> 2, g = i2 & 3u, row = g * 256 + j;
            ws[idx] = bih1[row] + bhh1[row];
        }
    }
}

__global__ __launch_bounds__(256) void zero_state(float* __restrict__ ws) {
    const unsigned n = WS_FLOATS - OFF_H0;
    for (unsigned i = blockIdx.x * blockDim.x + threadIdx.x; i < n;
         i += gridDim.x * blockDim.x)
        ws[OFF_H0 + i] = 0.0f;
}

// One iteration of the software-pipelined time loop:
//   blocks [0,128)   : layer-1 LSTM cell for step t-1
//   blocks [128,256) : layer-0 LSTM cell for step t
//   blocks [256,288) : fc1+relu+fc2-partials for step t-2
//   block  288       : fc2 final reduce for step t-3
__global__ __launch_bounds__(256, 2) void lstm_step(
    const float* __restrict__ x,
    const float* __restrict__ fc1w, const float* __restrict__ fc1b,
    const float* __restrict__ fc2w, const float* __restrict__ fc2b,
    float* __restrict__ ws, float* __restrict__ out, int t)
{
    __shared__ __align__(16) float hl[64 * 68];   // [64 rows][64 k + pad 4]
    const int tid  = threadIdx.x;
    const int lane = tid & 63;
    const int wv   = __builtin_amdgcn_readfirstlane(tid >> 6);  // wave id 0..3 (SGPR)
    const int blk  = blockIdx.x;

    float* h0 = ws + OFF_H0;
    float* h1 = ws + OFF_H1;

    if (blk < 256) {
        // ---------------- LSTM roles ----------------
        const bool isL1 = (blk < 128);
        const int  s    = isL1 ? (t - 1) : t;
        if (s < 0 || s >= TSTEPS) return;
        const int bb = isL1 ? blk : (blk - 128);
        const int rb = bb >> 5;               // 0..3   (64 rows each)
        const int jb = bb & 31;               // 0..31  (8 j each)
        const int r0 = rb * 64;
        const int j0 = jb * 8 + wv * 2;       // wave's two j columns
        const int ra = r0 + lane;             // this lane's batch row

        const float* Wg  = ws + (isL1 ? OFF_WG1S : OFF_WG0HS);
        const float* bs  = ws + (isL1 ? OFF_BS1 : OFF_BS0);
        // L1 reads h0(s) [written by L0 last iter]; L0 reads h0(s-1)
        const float* srcA = isL1 ? (h0 + (s & 1) * (BB * HH))
                                 : (h0 + ((s + 1) & 1) * (BB * HH));
        const float* srcB = h1 + ((s + 1) & 1) * (BB * HH);   // h1(s-1), L1 only
        float* hw = isL1 ? (h1 + (s & 1) * (BB * HH))
                         : (h0 + (s & 1) * (BB * HH));
        float* cT = ws + (isL1 ? OFF_C1T : OFF_C0T);

        float acc0[4] = {0.f, 0.f, 0.f, 0.f};
        float acc1[4] = {0.f, 0.f, 0.f, 0.f};

        const int nchunk  = isL1 ? 8 : 4;
        const int wstride = isL1 ? 2048 : 1024;  // floats per j in Wg

        auto stage_ld = [&](int c, float4* st) {
            const int kc = c * 64;
            const float* src = (isL1 && c >= 4) ? (srcB + (kc - 256)) : (srcA + kc);
            #pragma unroll
            for (int i = 0; i < 4; ++i) {
                int f = tid + i * 256;
                int row = f >> 4, kq = f & 15;
                st[i] = *(const float4*)(src + (size_t)(r0 + row) * HH + kq * 4);
            }
        };
        auto stage_st = [&](const float4* st) {
            #pragma unroll
            for (int i = 0; i < 4; ++i) {
                int f = tid + i * 256;
                int row = f >> 4, kq = f & 15;
                *(float4*)&hl[row * 68 + kq * 4] = st[i];
            }
        };

        float4 st[4];
        stage_ld(0, st);   // prefetch first h chunk (registers only)

        // ---- L0 input projection (K=16 from x_t) ----
        if (!isL1) {
            {
                int row = tid >> 2, kq = tid & 3;
                *(float4*)&hl[row * 68 + kq * 4] =
                    *(const float4*)(x + (size_t)(r0 + row) * (TSTEPS * INPUT)
                                       + s * INPUT + kq * 4);
            }
            __syncthreads();
            const float* w0 = ws + OFF_WG0XS;
            #pragma unroll
            for (int kk = 0; kk < 4; ++kk) {
                float4 hv = *(const float4*)&hl[lane * 68 + kk * 4];
                #pragma unroll
                for (int jj = 0; jj < 2; ++jj) {
                    const float* wj = w0 + (size_t)(j0 + jj) * 64 + kk * 16;  // uniform -> s_load
                    float* acc = jj ? acc1 : acc0;
                    #pragma unroll
                    for (int g = 0; g < 4; ++g) {
                        acc[g] = fmaf(hv.x, wj[g * 4 + 0], acc[g]);
                        acc[g] = fmaf(hv.y, wj[g * 4 + 1], acc[g]);
                        acc[g] = fmaf(hv.z, wj[g * 4 + 2], acc[g]);
                        acc[g] = fmaf(hv.w, wj[g * 4 + 3], acc[g]);
                    }
                }
            }
            __syncthreads();
        }

        // ---- recurrent projection, K chunks of 64, pipelined staging ----
        for (int c = 0; c < nchunk; ++c) {
            stage_st(st);
            __syncthreads();
            if (c + 1 < nchunk) stage_ld(c + 1, st);   // overlap with compute
            const int kqb = c * 16;
            #pragma unroll
            for (int kk = 0; kk < 16; ++kk) {
                float4 hv = *(const float4*)&hl[lane * 68 + kk * 4];
                #pragma unroll
                for (int jj = 0; jj < 2; ++jj) {
                    const float* wj = Wg + (size_t)(j0 + jj) * wstride + (kqb + kk) * 16;
                    float* acc = jj ? acc1 : acc0;
                    #pragma unroll
                    for (int g = 0; g < 4; ++g) {
                        acc[g] = fmaf(hv.x, wj[g * 4 + 0], acc[g]);
                        acc[g] = fmaf(hv.y, wj[g * 4 + 1], acc[g]);
                        acc[g] = fmaf(hv.z, wj[g * 4 + 2], acc[g]);
                        acc[g] = fmaf(hv.w, wj[g * 4 + 3], acc[g]);
                    }
                }
            }
            __syncthreads();
        }

        // ---- cell update (gate order i,f,g,o) ----
        #pragma unroll
        for (int jj = 0; jj < 2; ++jj) {
            const int j = j0 + jj;
            float* acc = jj ? acc1 : acc0;
            float ig = sigmoidf_(acc[0] + bs[j * 4 + 0]);
            float fg = sigmoidf_(acc[1] + bs[j * 4 + 1]);
            float gg = tanhf    (acc[2] + bs[j * 4 + 2]);
            float og = sigmoidf_(acc[3] + bs[j * 4 + 3]);
            float cp = cT[j * BB + ra];
            float cn = fg * cp + ig * gg;
            cT[j * BB + ra] = cn;
            hw[(size_t)ra * HH + j] = og * tanhf(cn);
        }
    } else if (blk < 288) {
        // ---------------- FC-A: fc1 + relu + fc2 partials for step t-2 ----------------
        const int tt = t - 2;
        if (tt < 0 || tt >= TSTEPS) return;
        const int bb = blk - 256;             // 0..31
        const int rb = bb >> 3, jb = bb & 7;
        const int r0 = rb * 64;
        const int j0 = jb * 32 + wv * 8;      // wave's 8 fc1 outputs
        const float* hs = h1 + (tt & 1) * (BB * HH);

        float acc[8] = {0.f, 0.f, 0.f, 0.f, 0.f, 0.f, 0.f, 0.f};

        float4 st[4];
        {   // prefetch chunk 0
            #pragma unroll
            for (int i = 0; i < 4; ++i) {
                int f = tid + i * 256;
                int row = f >> 4, kq = f & 15;
                st[i] = *(const float4*)(hs + (size_t)(r0 + row) * HH + kq * 4);
            }
        }
        for (int c = 0; c < 4; ++c) {
            #pragma unroll
            for (int i = 0; i < 4; ++i) {
                int f = tid + i * 256;
                int row = f >> 4, kq = f & 15;
                *(float4*)&hl[row * 68 + kq * 4] = st[i];
            }
            __syncthreads();
            if (c + 1 < 4) {
                const int kc = (c + 1) * 64;
                #pragma unroll
                for (int i = 0; i < 4; ++i) {
                    int f = tid + i * 256;
                    int row = f >> 4, kq = f & 15;
                    st[i] = *(const float4*)(hs + (size_t)(r0 + row) * HH + kc + kq * 4);
                }
            }
            const int kc = c * 64;
            #pragma unroll
            for (int kk = 0; kk < 16; ++kk) {
                float4 hv = *(const float4*)&hl[lane * 68 + kk * 4];
                #pragma unroll
                for (int jj = 0; jj < 8; ++jj) {
                    const float* wj = fc1w + (size_t)(j0 + jj) * HH + kc + kk * 4; // uniform
                    acc[jj] = fmaf(hv.x, wj[0], acc[jj]);
                    acc[jj] = fmaf(hv.y, wj[1], acc[jj]);
                    acc[jj] = fmaf(hv.z, wj[2], acc[jj]);
                    acc[jj] = fmaf(hv.w, wj[3], acc[jj]);
                }
            }
            __syncthreads();
        }
        float p = 0.f;
        #pragma unroll
        for (int jj = 0; jj < 8; ++jj) {
            const int j = j0 + jj;
            float v = acc[jj] + fc1b[j];
            v = v > 0.f ? v : 0.f;
            p = fmaf(fc2w[j], v, p);
        }
        __syncthreads();
        hl[wv * 64 + lane] = p;               // reduce 4 waves
        __syncthreads();
        if (tid < 64) {
            float s4 = hl[tid] + hl[64 + tid] + hl[128 + tid] + hl[192 + tid];
            ws[OFF_PB + (unsigned)(t & 1) * 2048u + (unsigned)jb * 256u + r0 + tid] = s4;
        }
    } else {
        // ---------------- FC-B: final fc2 reduce for step t-3 ----------------
        const int tt = t - 3;
        if (tt < 0 || tt >= TSTEPS) return;
        const float* pb = ws + OFF_PB + (unsigned)((t - 1) & 1) * 2048u;
        float s = fc2b[0];
        #pragma unroll
        for (int jb = 0; jb < 8; ++jb) s += pb[jb * 256 + tid];
        out[(size_t)tid * TSTEPS + tt] = s;
    }
}

extern "C" void kernel_launch(void* const* d_in, const int* in_sizes, int n_in,
                              void* d_out, int out_size, void* d_ws, size_t ws_size,
                              hipStream_t stream)
{
    const float* x    = (const float*)d_in[0];
    const float* Wih0 = (const float*)d_in[1];
    const float* Whh0 = (const float*)d_in[2];
    const float* bih0 = (const float*)d_in[3];
    const float* bhh0 = (const float*)d_in[4];
    const float* Wih1 = (const float*)d_in[5];
    const float* Whh1 = (const float*)d_in[6];
    const float* bih1 = (const float*)d_in[7];
    const float* bhh1 = (const float*)d_in[8];
    const float* fc1w = (const float*)d_in[9];
    const float* fc1b = (const float*)d_in[10];
    const float* fc2w = (const float*)d_in[11];
    const float* fc2b = (const float*)d_in[12];
    float* ws  = (float*)d_ws;
    float* out = (float*)d_out;

    prep_kernel<<<512, 256, 0, stream>>>(Wih0, Whh0, bih0, bhh0,
                                         Wih1, Whh1, bih1, bhh1, ws);
    zero_state<<<512, 256, 0, stream>>>(ws);

    for (int t = 0; t < TSTEPS + 3; ++t)
        lstm_step<<<289, 256, 0, stream>>>(x, fc1w, fc1b, fc2w, fc2b, ws, out, t);
}

// Round 2
// 30683.752 us; speedup vs baseline: 1.5148x; 1.5148x over previous
//
#include <hip/hip_runtime.h>
#include <math.h>

#define TSTEPS 1024
#define BB 256
#define HH 256
#define INPUT 16

// ---- workspace layout (float offsets) ----
// Read-only after prep (accessed via `wro` restrict pointer in lstm_step):
//   Wg1s  [256 j][128 kq][4 gate][4 ki]
//   Wg0hs [256 j][ 64 kq][4][4]
//   Wg0xs [256 j][  4 kq][4][4]
//   bs0/bs1 [256 j][4 gate]
// Mutable state (accessed via `hrw` restrict pointer):
//   h0/h1 [2 buf][256 r][256 j], c0T/c1T [256 j][256 r], pbuf [2][8 jb][256 r]
#define OFF_WG1S  0u
#define OFF_WG0HS 524288u
#define OFF_WG0XS 786432u
#define OFF_BS0   802816u
#define OFF_BS1   803840u
#define OFF_H0    804864u
#define OFF_H1    935936u
#define OFF_C0T   1067008u
#define OFF_C1T   1132544u
#define OFF_PB    1198080u
#define WS_FLOATS 1202176u

__device__ __forceinline__ float fast_sigmoid(float v) {
    return __builtin_amdgcn_rcpf(1.0f + __expf(-v));
}
__device__ __forceinline__ float fast_tanh(float v) {
    return 1.0f - 2.0f * __builtin_amdgcn_rcpf(1.0f + __expf(2.0f * v));
}

__global__ __launch_bounds__(256) void prep_kernel(
    const float* __restrict__ Wih0, const float* __restrict__ Whh0,
    const float* __restrict__ bih0, const float* __restrict__ bhh0,
    const float* __restrict__ Wih1, const float* __restrict__ Whh1,
    const float* __restrict__ bih1, const float* __restrict__ bhh1,
    float* __restrict__ ws)
{
    for (unsigned idx = blockIdx.x * blockDim.x + threadIdx.x; idx < 804864u;
         idx += gridDim.x * blockDim.x) {
        if (idx < 524288u) {                       // Wg1s
            unsigned j = idx >> 11, rem = idx & 2047u;
            unsigned kq = rem >> 4, g = (rem >> 2) & 3u, ki = rem & 3u;
            unsigned k = kq * 4 + ki, row = g * 256 + j;
            ws[idx] = (k < 256u) ? Wih1[row * 256 + k] : Whh1[row * 256 + (k - 256u)];
        } else if (idx < 786432u) {                // Wg0hs
            unsigned i2 = idx - 524288u;
            unsigned j = i2 >> 10, rem = i2 & 1023u;
            unsigned kq = rem >> 4, g = (rem >> 2) & 3u, ki = rem & 3u;
            unsigned k = kq * 4 + ki, row = g * 256 + j;
            ws[idx] = Whh0[row * 256 + k];
        } else if (idx < 802816u) {                // Wg0xs
            unsigned i2 = idx - 786432u;
            unsigned j = i2 >> 6, rem = i2 & 63u;
            unsigned kq = rem >> 4, g = (rem >> 2) & 3u, ki = rem & 3u;
            unsigned k = kq * 4 + ki, row = g * 256 + j;
            ws[idx] = Wih0[row * 16 + k];
        } else if (idx < 803840u) {                // bs0
            unsigned i2 = idx - 802816u;
            unsigned j = i2 >> 2, g = i2 & 3u, row = g * 256 + j;
            ws[idx] = bih0[row] + bhh0[row];
        } else {                                   // bs1
            unsigned i2 = idx - 803840u;
            unsigned j = i2 >> 2, g = i2 & 3u, row = g * 256 + j;
            ws[idx] = bih1[row] + bhh1[row];
        }
    }
}

__global__ __launch_bounds__(256) void zero_state(float* __restrict__ ws) {
    const unsigned n = WS_FLOATS - OFF_H0;
    for (unsigned i = blockIdx.x * blockDim.x + threadIdx.x; i < n;
         i += gridDim.x * blockDim.x)
        ws[OFF_H0 + i] = 0.0f;
}

// Software-pipelined time loop, one launch per iteration.
// Role order chosen so the doubled CUs (blocks 256+ land on CUs 0..32) pair a
// 1-unit FC-A block with a 1-unit L0 block -> max 2 units per CU everywhere:
//   blocks [0,128)   : layer-0 LSTM cell, step t      (1 unit, K=256)
//   blocks [128,256) : layer-1 LSTM cell, step t-1    (2 units, K=512)
//   blocks [256,288) : fc1+relu+fc2 partials, step t-2 (1 unit)
//   block  288       : fc2 final reduce, step t-3
// Weights come in via `wro` (restrict, read-only region of ws) so uniform
// weight loads can scalarize to s_load; state via `hrw` (disjoint region).
__global__ __launch_bounds__(256, 2) void lstm_step(
    const float* __restrict__ x,
    const float* __restrict__ fc1w, const float* __restrict__ fc1b,
    const float* __restrict__ fc2w, const float* __restrict__ fc2b,
    const float* __restrict__ wro, float* __restrict__ hrw,
    float* __restrict__ out, int t)
{
    __shared__ __align__(16) float hl[64 * 68];   // [64 rows][64 k + pad 4]
    const int tid  = threadIdx.x;
    const int lane = tid & 63;
    const int wv   = __builtin_amdgcn_readfirstlane(tid >> 6);  // wave id 0..3
    const int blk  = blockIdx.x;

    float* h0 = hrw + OFF_H0;
    float* h1 = hrw + OFF_H1;

    if (blk < 256) {
        // ---------------- LSTM roles ----------------
        const bool isL1 = (blk >= 128);
        const int  s    = isL1 ? (t - 1) : t;
        if (s < 0 || s >= TSTEPS) return;
        const int bb = isL1 ? (blk - 128) : blk;
        const int rb = bb >> 5;               // 0..3   (64 rows each)
        const int jb = bb & 31;               // 0..31  (8 j each)
        const int r0 = rb * 64;
        const int j0 = jb * 8 + wv * 2;       // wave's two j columns (uniform)
        const int ra = r0 + lane;             // this lane's batch row

        const float* Wg  = wro + (isL1 ? OFF_WG1S : OFF_WG0HS);
        const float* bs  = wro + (isL1 ? OFF_BS1 : OFF_BS0);
        // L1 reads h0(s) [written by L0 last iter]; L0 reads h0(s-1)
        const float* srcA = isL1 ? (h0 + (s & 1) * (BB * HH))
                                 : (h0 + ((s + 1) & 1) * (BB * HH));
        const float* srcB = h1 + ((s + 1) & 1) * (BB * HH);   // h1(s-1), L1 only
        float* hw = isL1 ? (h1 + (s & 1) * (BB * HH))
                         : (h0 + (s & 1) * (BB * HH));
        float* cT = hrw + (isL1 ? OFF_C1T : OFF_C0T);

        float acc0[4] = {0.f, 0.f, 0.f, 0.f};
        float acc1[4] = {0.f, 0.f, 0.f, 0.f};

        const int nchunk  = isL1 ? 8 : 4;
        const int wstride = isL1 ? 2048 : 1024;  // floats per j in Wg

        auto stage_ld = [&](int c, float4* st) {
            const int kc = c * 64;
            const float* src = (isL1 && c >= 4) ? (srcB + (kc - 256)) : (srcA + kc);
            #pragma unroll
            for (int i = 0; i < 4; ++i) {
                int f = tid + i * 256;
                int row = f >> 4, kq = f & 15;
                st[i] = *(const float4*)(src + (size_t)(r0 + row) * HH + kq * 4);
            }
        };
        auto stage_st = [&](const float4* st) {
            #pragma unroll
            for (int i = 0; i < 4; ++i) {
                int f = tid + i * 256;
                int row = f >> 4, kq = f & 15;
                *(float4*)&hl[row * 68 + kq * 4] = st[i];
            }
        };

        float4 st[4];
        stage_ld(0, st);   // prefetch first h chunk (registers only)

        // ---- L0 input projection (K=16 from x_t) ----
        if (!isL1) {
            {
                int row = tid >> 2, kq = tid & 3;
                *(float4*)&hl[row * 68 + kq * 4] =
                    *(const float4*)(x + (size_t)(r0 + row) * (TSTEPS * INPUT)
                                       + s * INPUT + kq * 4);
            }
            __syncthreads();
            const float* w0 = wro + OFF_WG0XS;
            #pragma unroll
            for (int kk = 0; kk < 4; ++kk) {
                float4 hv = *(const float4*)&hl[lane * 68 + kk * 4];
                #pragma unroll
                for (int jj = 0; jj < 2; ++jj) {
                    const float* wj = w0 + (size_t)(j0 + jj) * 64 + kk * 16;  // uniform
                    float* acc = jj ? acc1 : acc0;
                    #pragma unroll
                    for (int g = 0; g < 4; ++g) {
                        acc[g] = fmaf(hv.x, wj[g * 4 + 0], acc[g]);
                        acc[g] = fmaf(hv.y, wj[g * 4 + 1], acc[g]);
                        acc[g] = fmaf(hv.z, wj[g * 4 + 2], acc[g]);
                        acc[g] = fmaf(hv.w, wj[g * 4 + 3], acc[g]);
                    }
                }
            }
            __syncthreads();
        }

        // ---- recurrent projection, K chunks of 64, pipelined staging ----
        for (int c = 0; c < nchunk; ++c) {
            stage_st(st);
            __syncthreads();
            if (c + 1 < nchunk) stage_ld(c + 1, st);   // overlap with compute
            const int kqb = c * 16;
            #pragma unroll
            for (int kk = 0; kk < 16; ++kk) {
                float4 hv = *(const float4*)&hl[lane * 68 + kk * 4];
                #pragma unroll
                for (int jj = 0; jj < 2; ++jj) {
                    const float* wj = Wg + (size_t)(j0 + jj) * wstride + (kqb + kk) * 16;
                    float* acc = jj ? acc1 : acc0;
                    #pragma unroll
                    for (int g = 0; g < 4; ++g) {
                        acc[g] = fmaf(hv.x, wj[g * 4 + 0], acc[g]);
                        acc[g] = fmaf(hv.y, wj[g * 4 + 1], acc[g]);
                        acc[g] = fmaf(hv.z, wj[g * 4 + 2], acc[g]);
                        acc[g] = fmaf(hv.w, wj[g * 4 + 3], acc[g]);
                    }
                }
            }
            __syncthreads();
        }

        // ---- cell update (gate order i,f,g,o) ----
        #pragma unroll
        for (int jj = 0; jj < 2; ++jj) {
            const int j = j0 + jj;
            float* acc = jj ? acc1 : acc0;
            float ig = fast_sigmoid(acc[0] + bs[j * 4 + 0]);
            float fg = fast_sigmoid(acc[1] + bs[j * 4 + 1]);
            float gg = fast_tanh   (acc[2] + bs[j * 4 + 2]);
            float og = fast_sigmoid(acc[3] + bs[j * 4 + 3]);
            float cp = cT[j * BB + ra];
            float cn = fg * cp + ig * gg;
            cT[j * BB + ra] = cn;
            hw[(size_t)ra * HH + j] = og * fast_tanh(cn);
        }
    } else if (blk < 288) {
        // ---------------- FC-A: fc1 + relu + fc2 partials for step t-2 ----------------
        const int tt = t - 2;
        if (tt < 0 || tt >= TSTEPS) return;
        const int bb = blk - 256;             // 0..31
        const int rb = bb >> 3, jb = bb & 7;
        const int r0 = rb * 64;
        const int j0 = jb * 32 + wv * 8;      // wave's 8 fc1 outputs (uniform)
        const float* hs = h1 + (tt & 1) * (BB * HH);

        float acc[8] = {0.f, 0.f, 0.f, 0.f, 0.f, 0.f, 0.f, 0.f};

        float4 st[4];
        {   // prefetch chunk 0
            #pragma unroll
            for (int i = 0; i < 4; ++i) {
                int f = tid + i * 256;
                int row = f >> 4, kq = f & 15;
                st[i] = *(const float4*)(hs + (size_t)(r0 + row) * HH + kq * 4);
            }
        }
        for (int c = 0; c < 4; ++c) {
            #pragma unroll
            for (int i = 0; i < 4; ++i) {
                int f = tid + i * 256;
                int row = f >> 4, kq = f & 15;
                *(float4*)&hl[row * 68 + kq * 4] = st[i];
            }
            __syncthreads();
            if (c + 1 < 4) {
                const int kc = (c + 1) * 64;
                #pragma unroll
                for (int i = 0; i < 4; ++i) {
                    int f = tid + i * 256;
                    int row = f >> 4, kq = f & 15;
                    st[i] = *(const float4*)(hs + (size_t)(r0 + row) * HH + kc + kq * 4);
                }
            }
            const int kc = c * 64;
            #pragma unroll
            for (int kk = 0; kk < 16; ++kk) {
                float4 hv = *(const float4*)&hl[lane * 68 + kk * 4];
                #pragma unroll
                for (int jj = 0; jj < 8; ++jj) {
                    const float* wj = fc1w + (size_t)(j0 + jj) * HH + kc + kk * 4; // uniform
                    acc[jj] = fmaf(hv.x, wj[0], acc[jj]);
                    acc[jj] = fmaf(hv.y, wj[1], acc[jj]);
                    acc[jj] = fmaf(hv.z, wj[2], acc[jj]);
                    acc[jj] = fmaf(hv.w, wj[3], acc[jj]);
                }
            }
            __syncthreads();
        }
        float p = 0.f;
        #pragma unroll
        for (int jj = 0; jj < 8; ++jj) {
            const int j = j0 + jj;
            float v = acc[jj] + fc1b[j];
            v = v > 0.f ? v : 0.f;
            p = fmaf(fc2w[j], v, p);
        }
        __syncthreads();
        hl[wv * 64 + lane] = p;               // reduce 4 waves
        __syncthreads();
        if (tid < 64) {
            float s4 = hl[tid] + hl[64 + tid] + hl[128 + tid] + hl[192 + tid];
            hrw[OFF_PB + (unsigned)(t & 1) * 2048u + (unsigned)jb * 256u + r0 + tid] = s4;
        }
    } else {
        // ---------------- FC-B: final fc2 reduce for step t-3 ----------------
        const int tt = t - 3;
        if (tt < 0 || tt >= TSTEPS) return;
        const float* pb = hrw + OFF_PB + (unsigned)((t - 1) & 1) * 2048u;
        float s = fc2b[0];
        #pragma unroll
        for (int jb = 0; jb < 8; ++jb) s += pb[jb * 256 + tid];
        out[(size_t)tid * TSTEPS + tt] = s;
    }
}

extern "C" void kernel_launch(void* const* d_in, const int* in_sizes, int n_in,
                              void* d_out, int out_size, void* d_ws, size_t ws_size,
                              hipStream_t stream)
{
    const float* x    = (const float*)d_in[0];
    const float* Wih0 = (const float*)d_in[1];
    const float* Whh0 = (const float*)d_in[2];
    const float* bih0 = (const float*)d_in[3];
    const float* bhh0 = (const float*)d_in[4];
    const float* Wih1 = (const float*)d_in[5];
    const float* Whh1 = (const float*)d_in[6];
    const float* bih1 = (const float*)d_in[7];
    const float* bhh1 = (const float*)d_in[8];
    const float* fc1w = (const float*)d_in[9];
    const float* fc1b = (const float*)d_in[10];
    const float* fc2w = (const float*)d_in[11];
    const float* fc2b = (const float*)d_in[12];
    float* ws  = (float*)d_ws;
    float* out = (float*)d_out;

    prep_kernel<<<512, 256, 0, stream>>>(Wih0, Whh0, bih0, bhh0,
                                         Wih1, Whh1, bih1, bhh1, ws);
    zero_state<<<512, 256, 0, stream>>>(ws);

    for (int t = 0; t < TSTEPS + 3; ++t)
        lstm_step<<<289, 256, 0, stream>>>(x, fc1w, fc1b, fc2w, fc2b,
                                           ws, ws, out, t);
}